// Round 1
// baseline (156.177 us; speedup 1.0000x reference)
//
#include <hip/hip_runtime.h>
#include <hip/hip_bf16.h>
#include <stdint.h>

#define CIN   512
#define COUT  512
#define BM    128
#define BN    128
#define NIB   16            // 512/32 i-blocks
#define KSTEPS 128          // NIB * 8 degrees (d=1..8); d=0 folded into bias

typedef float f32x4 __attribute__((ext_vector_type(4)));
typedef short s16x8 __attribute__((ext_vector_type(8)));

// Frag-packed bf16 weights: [ks(128)][cg(32)][lane(64)] of 8 bf16 (16B)
__device__ uint4 Wp_g[KSTEPS * 32 * 64];   // 4 MB
__device__ float bias_g[COUT];

__device__ __forceinline__ unsigned short f2bf(float f) {
  uint32_t x = __float_as_uint(f);
  return (unsigned short)((x + 0x7fffu + ((x >> 16) & 1u)) >> 16);  // RNE
}

__device__ __forceinline__ float ftanh(float v) {
  float e = __expf(v + v);                       // v_exp_f32 path
  return 1.0f - __fdividef(2.0f, e + 1.0f);      // exact at +/-inf saturation
}

// ---- pack weights into MFMA B-fragment order, bf16 ----
// Wp[ks][cg][lane] holds B[k = 8*(lane>>4)+j][n = lane&15] for the K=32 slice:
// ks = ib*8 + (d-1);  k -> i = ib*32 + k;  n -> o = cg*16 + n.
__global__ void pack_w(const float* __restrict__ cw) {
  int t  = blockIdx.x >> 5;         // 0..127
  int cg = blockIdx.x & 31;
  int l  = threadIdx.x;             // 0..63
  int ib = t >> 3;
  int d  = (t & 7) + 1;
  int i0 = ib * 32 + (l >> 4) * 8;
  int o  = cg * 16 + (l & 15);
  uint32_t p[4];
  #pragma unroll
  for (int q = 0; q < 4; ++q) {
    float a = cw[(size_t)(i0 + 2*q    ) * (COUT*9) + o*9 + d];
    float b = cw[(size_t)(i0 + 2*q + 1) * (COUT*9) + o*9 + d];
    p[q] = (uint32_t)f2bf(a) | ((uint32_t)f2bf(b) << 16);
  }
  Wp_g[(t * 32 + cg) * 64 + l] = make_uint4(p[0], p[1], p[2], p[3]);
}

// ---- bias[o] = sum_i C[i][o][0]  (the d=0 / T_0==1 term) ----
__global__ void bias_k(const float* __restrict__ cw) {
  __shared__ float red[256];
  int o  = blockIdx.x * 64 + (threadIdx.x & 63);
  int ch = threadIdx.x >> 6;
  float s = 0.f;
  for (int i = ch * 128; i < ch * 128 + 128; ++i)
    s += cw[(size_t)i * (COUT*9) + o*9 + 0];
  red[threadIdx.x] = s;
  __syncthreads();
  if (threadIdx.x < 64) {
    int t = threadIdx.x;
    bias_g[blockIdx.x * 64 + t] = red[t] + red[t+64] + red[t+128] + red[t+192];
  }
}

// ---- fused basis-generation + GEMM ----
// 128x128 tile, 4 waves (each 64x64), A generated via Chebyshev recurrence
// into double-buffered LDS (half-i-block granularity), B direct global->reg.
__global__ void __launch_bounds__(256, 2) cheby_gemm(const float* __restrict__ x,
                                                     float* __restrict__ out) {
  __shared__ uint4 lds[2 * 4 * 4 * BM];   // [buf][slot(4 d)][h(4)][row(128)] = 64 KB
  const int tid  = threadIdx.x;
  const int lane = tid & 63;
  const int l15  = lane & 15;
  const int lh   = lane >> 4;
  const int w    = tid >> 6;
  const int wr   = w >> 1;
  const int wc   = w & 1;

  // bijective XCD swizzle (512 blocks, 512 % 8 == 0)
  int b0  = blockIdx.x;
  int bid = (b0 & 7) * 64 + (b0 >> 3);
  const int rb = (bid >> 2) * BM;
  const int cb = (bid & 3) * BN;
  const int cgbase = (cb >> 4) + wc * 4;

  // generator mapping: thread -> (row, 16 contiguous i-elements)
  const int grow = tid >> 1;
  const int ge   = tid & 1;
  const float* xrow = x + (size_t)(rb + grow) * CIN + ge * 16;

  // accumulators, initialized with the d=0 bias term
  f32x4 acc[4][4];
  #pragma unroll
  for (int cf = 0; cf < 4; ++cf) {
    float bv = bias_g[cb + wc*64 + cf*16 + l15];
    #pragma unroll
    for (int rf = 0; rf < 4; ++rf) {
      acc[rf][cf][0] = bv; acc[rf][cf][1] = bv;
      acc[rf][cf][2] = bv; acc[rf][cf][3] = bv;
    }
  }

  float xv[16], u2[16], tm1[16], tm2[16];

  auto loadX = [&](int ib) {
    const float4* p = reinterpret_cast<const float4*>(xrow + ib * 32);
    #pragma unroll
    for (int q = 0; q < 4; ++q) {
      float4 v = p[q];
      xv[4*q+0] = v.x; xv[4*q+1] = v.y; xv[4*q+2] = v.z; xv[4*q+3] = v.w;
    }
  };
  auto compute_u = [&]() {
    #pragma unroll
    for (int k = 0; k < 16; ++k) {
      float u = ftanh(ftanh(xv[k]));
      tm1[k] = u; tm2[k] = 1.0f; u2[k] = u + u;
    }
  };
  auto advance = [&]() {
    #pragma unroll
    for (int k = 0; k < 16; ++k) {
      float t = __builtin_fmaf(u2[k], tm1[k], -tm2[k]);
      tm2[k] = tm1[k]; tm1[k] = t;
    }
  };
  auto emit = [&](int buf, int slot) {   // write current tm1[] (= T_d) as bf16
    uint32_t p0[4], p1[4];
    #pragma unroll
    for (int q = 0; q < 4; ++q) {
      p0[q] = (uint32_t)f2bf(tm1[2*q])   | ((uint32_t)f2bf(tm1[2*q+1])   << 16);
      p1[q] = (uint32_t)f2bf(tm1[8+2*q]) | ((uint32_t)f2bf(tm1[8+2*q+1]) << 16);
    }
    int base = (buf * 4 + slot) * 4;
    lds[(base + 2*ge    ) * BM + grow] = make_uint4(p0[0], p0[1], p0[2], p0[3]);
    lds[(base + 2*ge + 1) * BM + grow] = make_uint4(p1[0], p1[1], p1[2], p1[3]);
  };

  s16x8 bcur[4], bnxt[4];
  auto loadB = [&](s16x8* dst, int ks) {
    #pragma unroll
    for (int cf = 0; cf < 4; ++cf) {
      uint4 v = Wp_g[(ks * 32 + cgbase + cf) * 64 + lane];
      dst[cf] = __builtin_bit_cast(s16x8, v);
    }
  };
  auto mfma_step = [&](int buf, int slot) {
    s16x8 a[4];
    int base = ((buf * 4 + slot) * 4 + lh) * BM + wr * 64 + l15;
    #pragma unroll
    for (int rf = 0; rf < 4; ++rf)
      a[rf] = *reinterpret_cast<const s16x8*>(&lds[base + rf * 16]);
    #pragma unroll
    for (int rf = 0; rf < 4; ++rf) {
      #pragma unroll
      for (int cf = 0; cf < 4; ++cf)
        acc[rf][cf] = __builtin_amdgcn_mfma_f32_16x16x32_bf16(
            a[rf], bcur[cf], acc[rf][cf], 0, 0, 0);
    }
  };

  // ---- prologue: generate (ib=0, d=1..4) into buf0 ----
  loadX(0);
  compute_u();
  emit(0, 0);                 // d=1 : T_1 = u
  advance(); emit(0, 1);      // d=2
  advance(); emit(0, 2);      // d=3
  advance(); emit(0, 3);      // d=4
  loadB(bcur, 0);
  __syncthreads();

  for (int ib = 0; ib < NIB; ++ib) {
    if (ib + 1 < NIB) loadX(ib + 1);   // issue early; consumed 4 ksteps later

    // PART 0: consume buf0 (d=1..4); generate (ib, d=5..8) -> buf1
    #pragma unroll
    for (int j = 0; j < 4; ++j) {
      int ks = ib * 8 + j;
      loadB(bnxt, ks + 1);             // ks+1 <= 124 always here
      mfma_step(0, j);
      advance(); emit(1, j);           // d = 5+j
      #pragma unroll
      for (int cf = 0; cf < 4; ++cf) bcur[cf] = bnxt[cf];
    }
    __syncthreads();

    // PART 1: consume buf1 (d=5..8); generate (ib+1, d=1..4) -> buf0
    #pragma unroll
    for (int j = 0; j < 4; ++j) {
      int ks = ib * 8 + 4 + j;
      if (ks + 1 < KSTEPS) loadB(bnxt, ks + 1);
      mfma_step(1, j);
      if (ib + 1 < NIB) {
        if (j == 0) { compute_u(); emit(0, 0); }
        else        { advance();   emit(0, j); }
      }
      #pragma unroll
      for (int cf = 0; cf < 4; ++cf) bcur[cf] = bnxt[cf];
    }
    __syncthreads();
  }

  // ---- epilogue: C/D layout col = lane&15, row = (lane>>4)*4 + reg ----
  const int orow = rb + wr * 64 + lh * 4;
  const int ocol = cb + wc * 64 + l15;
  #pragma unroll
  for (int rf = 0; rf < 4; ++rf) {
    #pragma unroll
    for (int cf = 0; cf < 4; ++cf) {
      #pragma unroll
      for (int r = 0; r < 4; ++r)
        out[(size_t)(orow + rf * 16 + r) * COUT + ocol + cf * 16] = acc[rf][cf][r];
    }
  }
}

extern "C" void kernel_launch(void* const* d_in, const int* in_sizes, int n_in,
                              void* d_out, int out_size, void* d_ws, size_t ws_size,
                              hipStream_t stream) {
  const float* x  = (const float*)d_in[0];   // (16384, 512) fp32
  const float* cw = (const float*)d_in[1];   // (512, 512, 9) fp32
  float* out = (float*)d_out;                // (16384, 512) fp32

  pack_w<<<dim3(KSTEPS * 32), dim3(64), 0, stream>>>(cw);
  bias_k<<<dim3(8), dim3(256), 0, stream>>>(cw);
  cheby_gemm<<<dim3(512), dim3(256), 0, stream>>>(x, out);
}

// Round 2
// 91.177 us; speedup vs baseline: 1.7129x; 1.7129x over previous
//
#include <hip/hip_runtime.h>
#include <hip/hip_bf16.h>
#include <stdint.h>

#define CIN   512
#define COUT  512
#define BM    128
#define BN    256
#define NIB   16            // 512/32 i-blocks
#define KSTEPS 128          // NIB * 8 degrees (d=1..8); d=0 folded into bias

typedef float f32x4 __attribute__((ext_vector_type(4)));
typedef short s16x8 __attribute__((ext_vector_type(8)));

// Frag-packed bf16 weights: [ks(128)][cg(32)][lane(64)] of 8 bf16 (16B)
__device__ uint4 Wp_g[KSTEPS * 32 * 64];   // 4 MB
__device__ float bias_g[COUT];

__device__ __forceinline__ uint32_t cvtpk(float lo, float hi) {
  uint32_t r;
  asm("v_cvt_pk_bf16_f32 %0, %1, %2" : "=v"(r) : "v"(lo), "v"(hi));
  return r;  // low 16 = bf16(lo), high 16 = bf16(hi)
}

__device__ __forceinline__ float ftanh(float v) {
  float e = __expf(v + v);
  return 1.0f - __fdividef(2.0f, e + 1.0f);
}

// ---- pack weights into MFMA B-fragment order, bf16 (coalesced via LDS) ----
// Block = (ib, cg): stages cw[ib*32..+31][cg*16..+15][0..8] (18KB, contiguous
// 576B per i), then emits 8 ks-slices of 64 uint4 each.
// Wp[ks][cg][lane] holds B[k = 8*(lane>>4)+j][n = lane&15], ks = ib*8+(d-1).
__global__ void pack_w(const float* __restrict__ cw) {
  __shared__ float lf[32 * 144];
  int ib = blockIdx.x >> 5;
  int cg = blockIdx.x & 31;
  for (int r = threadIdx.x; r < 32 * 144; r += 256) {
    int il = r / 144;
    int rem = r - il * 144;
    lf[r] = cw[(size_t)(ib * 32 + il) * (COUT * 9) + cg * 144 + rem];
  }
  __syncthreads();
  for (int v = threadIdx.x; v < 512; v += 256) {
    int ksl = v >> 6;            // d-1
    int lane = v & 63;
    int d = ksl + 1;
    int lh = lane >> 4, l15 = lane & 15;
    uint32_t p[4];
    #pragma unroll
    for (int q = 0; q < 4; ++q) {
      float a = lf[(lh * 8 + 2 * q    ) * 144 + l15 * 9 + d];
      float b = lf[(lh * 8 + 2 * q + 1) * 144 + l15 * 9 + d];
      p[q] = cvtpk(a, b);
    }
    Wp_g[((ib * 8 + ksl) * 32 + cg) * 64 + lane] = make_uint4(p[0], p[1], p[2], p[3]);
  }
}

// ---- bias[o] = sum_i C[i][o][0] (d=0 / T_0==1 term): one block per o ----
__global__ void bias_k(const float* __restrict__ cw) {
  int o = blockIdx.x;
  int t = threadIdx.x;
  float s = 0.f;
  #pragma unroll
  for (int q = 0; q < 8; ++q)
    s += cw[(size_t)(t + 64 * q) * (COUT * 9) + o * 9];
  #pragma unroll
  for (int off = 32; off; off >>= 1) s += __shfl_down(s, off);
  if (t == 0) bias_g[o] = s;
}

// ---- fused basis-generation + GEMM ----
// 128x256 tile, 8 waves (2x4 grid of 64x64), grid=256 (1 block/CU).
// A generated via Chebyshev recurrence into double-buffered LDS
// (half-i-block granularity), B direct global->reg (L2-resident).
__global__ void __launch_bounds__(512, 2) cheby_gemm(const float* __restrict__ x,
                                                     float* __restrict__ out) {
  __shared__ uint4 lds[2 * 4 * 4 * BM];   // [buf][slot(4 d)][h(4)][row(128)] = 64 KB
  const int tid  = threadIdx.x;
  const int lane = tid & 63;
  const int l15  = lane & 15;
  const int lh   = lane >> 4;
  const int w    = tid >> 6;
  const int wr   = w >> 2;          // 2 row-groups of 64
  const int wc   = w & 3;           // 4 col-groups of 64

  // bijective XCD swizzle (256 blocks, 256 % 8 == 0)
  int b0  = blockIdx.x;
  int bid = (b0 & 7) * 32 + (b0 >> 3);
  const int rb  = (bid >> 1) * BM;
  const int cb  = bid & 1;
  const int ocb = cb * BN;
  const int cgbase = cb * 16 + wc * 4;

  // generator mapping: wave-contiguous LDS writes, 8 elems/thread
  const int ge   = w >> 1;                 // i-chunk of 8 (0..3)
  const int grow = (w & 1) * 64 + lane;    // row (0..127)
  const float* xrow = x + (size_t)(rb + grow) * CIN + ge * 8;

  // accumulators, initialized with the d=0 bias term
  f32x4 acc[4][4];
  #pragma unroll
  for (int cf = 0; cf < 4; ++cf) {
    float bv = bias_g[ocb + wc * 64 + cf * 16 + l15];
    #pragma unroll
    for (int rf = 0; rf < 4; ++rf) {
      acc[rf][cf][0] = bv; acc[rf][cf][1] = bv;
      acc[rf][cf][2] = bv; acc[rf][cf][3] = bv;
    }
  }

  float xv[8], u2[8], tm1[8], tm2[8];

  auto loadX = [&](int ib) {
    const float4* p = reinterpret_cast<const float4*>(xrow + ib * 32);
    float4 v0 = p[0], v1 = p[1];
    xv[0] = v0.x; xv[1] = v0.y; xv[2] = v0.z; xv[3] = v0.w;
    xv[4] = v1.x; xv[5] = v1.y; xv[6] = v1.z; xv[7] = v1.w;
  };
  auto compute_u = [&]() {
    #pragma unroll
    for (int k = 0; k < 8; ++k) {
      float u = ftanh(ftanh(xv[k]));
      tm1[k] = u; tm2[k] = 1.0f; u2[k] = u + u;
    }
  };
  auto advance = [&]() {
    #pragma unroll
    for (int k = 0; k < 8; ++k) {
      float t = __builtin_fmaf(u2[k], tm1[k], -tm2[k]);
      tm2[k] = tm1[k]; tm1[k] = t;
    }
  };
  auto emit = [&](int buf, int slot) {   // write current tm1[] (= T_d) as bf16
    uint32_t p0 = cvtpk(tm1[0], tm1[1]);
    uint32_t p1 = cvtpk(tm1[2], tm1[3]);
    uint32_t p2 = cvtpk(tm1[4], tm1[5]);
    uint32_t p3 = cvtpk(tm1[6], tm1[7]);
    lds[((buf * 4 + slot) * 4 + ge) * BM + grow] = make_uint4(p0, p1, p2, p3);
  };

  s16x8 bcur[4], bnxt[4];
  auto loadB = [&](s16x8* dst, int ks) {
    #pragma unroll
    for (int cf = 0; cf < 4; ++cf) {
      uint4 v = Wp_g[(ks * 32 + cgbase + cf) * 64 + lane];
      dst[cf] = __builtin_bit_cast(s16x8, v);
    }
  };
  auto mfma_step = [&](int buf, int slot) {
    s16x8 a[4];
    int base = ((buf * 4 + slot) * 4 + lh) * BM + wr * 64 + l15;
    #pragma unroll
    for (int rf = 0; rf < 4; ++rf)
      a[rf] = *reinterpret_cast<const s16x8*>(&lds[base + rf * 16]);
    #pragma unroll
    for (int rf = 0; rf < 4; ++rf) {
      #pragma unroll
      for (int cf = 0; cf < 4; ++cf)
        acc[rf][cf] = __builtin_amdgcn_mfma_f32_16x16x32_bf16(
            a[rf], bcur[cf], acc[rf][cf], 0, 0, 0);
    }
  };

  // ---- prologue: generate (ib=0, d=1..4) into buf0 ----
  loadX(0);
  compute_u();
  emit(0, 0);                 // d=1 : T_1 = u
  advance(); emit(0, 1);      // d=2
  advance(); emit(0, 2);      // d=3
  advance(); emit(0, 3);      // d=4
  loadB(bcur, 0);
  __syncthreads();

  for (int ib = 0; ib < NIB; ++ib) {
    if (ib + 1 < NIB) loadX(ib + 1);   // issue early; consumed 4 ksteps later

    // PART 0: consume buf0 (d=1..4); generate (ib, d=5..8) -> buf1
    #pragma unroll
    for (int j = 0; j < 4; ++j) {
      int ks = ib * 8 + j;
      loadB(bnxt, ks + 1);             // ks+1 <= 124 always here
      mfma_step(0, j);
      advance(); emit(1, j);           // d = 5+j
      #pragma unroll
      for (int cf = 0; cf < 4; ++cf) bcur[cf] = bnxt[cf];
    }
    __syncthreads();

    // PART 1: consume buf1 (d=5..8); generate (ib+1, d=1..4) -> buf0
    #pragma unroll
    for (int j = 0; j < 4; ++j) {
      int ks = ib * 8 + 4 + j;
      if (ks + 1 < KSTEPS) loadB(bnxt, ks + 1);
      mfma_step(1, j);
      if (ib + 1 < NIB) {
        if (j == 0) { compute_u(); emit(0, 0); }
        else        { advance();   emit(0, j); }
      }
      #pragma unroll
      for (int cf = 0; cf < 4; ++cf) bcur[cf] = bnxt[cf];
    }
    __syncthreads();
  }

  // ---- epilogue: C/D layout col = lane&15, row = (lane>>4)*4 + reg ----
  const int orow = rb + wr * 64 + lh * 4;
  const int ocol = ocb + wc * 64 + l15;
  #pragma unroll
  for (int rf = 0; rf < 4; ++rf) {
    #pragma unroll
    for (int cf = 0; cf < 4; ++cf) {
      #pragma unroll
      for (int r = 0; r < 4; ++r)
        out[(size_t)(orow + rf * 16 + r) * COUT + ocol + cf * 16] = acc[rf][cf][r];
    }
  }
}

extern "C" void kernel_launch(void* const* d_in, const int* in_sizes, int n_in,
                              void* d_out, int out_size, void* d_ws, size_t ws_size,
                              hipStream_t stream) {
  const float* x  = (const float*)d_in[0];   // (16384, 512) fp32
  const float* cw = (const float*)d_in[1];   // (512, 512, 9) fp32
  float* out = (float*)d_out;                // (16384, 512) fp32

  pack_w<<<dim3(512), dim3(256), 0, stream>>>(cw);
  bias_k<<<dim3(COUT), dim3(64), 0, stream>>>(cw);
  cheby_gemm<<<dim3(256), dim3(512), 0, stream>>>(x, out);
}